// Round 13
// baseline (323.048 us; speedup 1.0000x reference)
//
#include <hip/hip_runtime.h>
#include <hip/hip_bf16.h>

#define D_IN 256
#define D_OUT 64
#define BN_EPS 1e-5f

#define BINSHIFT 8                 // 256 nodes per bin
#define BINCAP 4608                // >= max edges per bin (mean 4092, +8 sigma)
#define PCHUNK 8192                // edges per k_part block

typedef __attribute__((ext_vector_type(4))) float floatx4;
typedef __attribute__((ext_vector_type(8))) __bf16 bf16x8;
typedef __attribute__((ext_vector_type(4))) unsigned uintx4;

// ---- fused prep + binned partition (+ global degree count) -----------------
// blocks 0..7 : W split into whi/wlo (MFMA B-fragment order)
// block  8    : BN scale/shift precompute
// blocks 9+   : edge partition chunks; bincur/deg pre-zeroed by one memset
__global__ __launch_bounds__(256) void k_prepart(
        const float* __restrict__ W, __bf16* __restrict__ whi, __bf16* __restrict__ wlo,
        const float* __restrict__ bias, const float* __restrict__ gamma,
        const float* __restrict__ beta, const float* __restrict__ rmean,
        const float* __restrict__ rvar,
        float* __restrict__ bnsc, float* __restrict__ bnsh,
        const int* __restrict__ ei, int* __restrict__ bincur, int* __restrict__ deg,
        unsigned* __restrict__ pairs, int E, int nbins) {
    int b = blockIdx.x, t = threadIdx.x;
    if (b < 8) {                       // W split: tid 0..2047
        int tid = b * 256 + t;
        int lane = tid & 63, c = (tid >> 6) & 7, tt = tid >> 9;
        int row = tt * 16 + (lane & 15);
        int k0 = c * 32 + (lane >> 4) * 8;
        size_t dst = (size_t)tid * 8;
        #pragma unroll
        for (int j = 0; j < 8; ++j) {
            float w = W[(size_t)row * D_IN + k0 + j];
            __bf16 h = (__bf16)w;
            whi[dst + j] = h;
            wlo[dst + j] = (__bf16)(w - (float)h);
        }
        return;
    }
    if (b == 8) {                      // BN params
        if (t < D_OUT) {
            float sc = rsqrtf(rvar[t] + BN_EPS) * gamma[t];
            bnsc[t] = sc;
            bnsh[t] = (bias[t] - rmean[t]) * sc + beta[t];
        }
        return;
    }

    // ---- partition role ----
    __shared__ int hist[512];
    __shared__ int base[512];
    int e0 = (b - 9) * PCHUNK;

    for (int j = t; j < nbins; j += 256) hist[j] = 0;
    __syncthreads();

    int cols[PCHUNK / 256];
    int rows[PCHUNK / 256];
    int ranks[PCHUNK / 256];
    #pragma unroll
    for (int i = 0; i < PCHUNK / 256; ++i) {
        int e = e0 + i * 256 + t;
        if (e < E) {
            int c = ei[E + e];
            cols[i] = c;
            rows[i] = ei[e];
            ranks[i] = atomicAdd(&hist[c >> BINSHIFT], 1);
            atomicAdd(&deg[c], 1);
        }
    }
    __syncthreads();
    for (int j = t; j < nbins; j += 256)
        base[j] = atomicAdd(&bincur[j], hist[j]);
    __syncthreads();
    #pragma unroll
    for (int i = 0; i < PCHUNK / 256; ++i) {
        int e = e0 + i * 256 + t;
        if (e < E) {
            int c = cols[i];
            int bin = c >> BINSHIFT;
            int pos = base[bin] + ranks[i];
            if (pos >= BINCAP) pos = BINCAP - 1;     // never-hit safety
            pairs[(size_t)bin * BINCAP + pos] =
                ((unsigned)rows[i] << 8) | (unsigned)(c & 255);
        }
    }
}

// ---- fused CSR fill + GEMM (disjoint block roles, no mutual dependency) ----
// blocks 0..nbins-1  : per-bin CSR fill (bin-offset scan + single-pass scatter)
// blocks nbins..     : y(bf16) = rsqrt(deg+1) * (x @ W^T), split-bf16 MFMA
__global__ __launch_bounds__(256) void k_fillgemm(
        const unsigned* __restrict__ pairs, const int* __restrict__ bincur,
        int* __restrict__ off, int* __restrict__ srcs,
        const float* __restrict__ x, const __bf16* __restrict__ whi,
        const __bf16* __restrict__ wlo, const int* __restrict__ deg,
        __bf16* __restrict__ yb, int n, int nbins) {
    __shared__ int hist[256];
    __shared__ int sc[256];
    __shared__ int nbase[256];
    __shared__ int sbase;
    int b = blockIdx.x, t = threadIdx.x;

    if (b >= nbins) {                  // ---------------- GEMM role ----------
        int wave = t >> 6;
        int lane = t & 63;
        int m0 = (b - nbins) * 64 + wave * 16;
        if (m0 >= n) return;
        int q = lane >> 4, cl = lane & 15;
        int arow = m0 + cl; if (arow >= n) arow = n - 1;   // clamp (tail rows unused)
        const float* ap = x + (size_t)arow * D_IN + q * 8;

        floatx4 acc[4] = {{0.f,0.f,0.f,0.f},{0.f,0.f,0.f,0.f},
                          {0.f,0.f,0.f,0.f},{0.f,0.f,0.f,0.f}};

        #pragma unroll
        for (int c = 0; c < 8; ++c) {
            floatx4 a0 = *(const floatx4*)(ap + c * 32);
            floatx4 a1 = *(const floatx4*)(ap + c * 32 + 4);
            bf16x8 ahi, alo;
            #pragma unroll
            for (int j = 0; j < 4; ++j) {
                __bf16 h0 = (__bf16)a0[j];
                __bf16 h1 = (__bf16)a1[j];
                ahi[j] = h0;     alo[j] = (__bf16)(a0[j] - (float)h0);
                ahi[4 + j] = h1; alo[4 + j] = (__bf16)(a1[j] - (float)h1);
            }
            #pragma unroll
            for (int u = 0; u < 4; ++u) {
                size_t fo = ((size_t)(u * 8 + c) * 64 + lane) * 8;
                bf16x8 bh = *(const bf16x8*)(whi + fo);
                bf16x8 bl = *(const bf16x8*)(wlo + fo);
                acc[u] = __builtin_amdgcn_mfma_f32_16x16x32_bf16(ahi, bh, acc[u], 0, 0, 0);
                acc[u] = __builtin_amdgcn_mfma_f32_16x16x32_bf16(alo, bh, acc[u], 0, 0, 0);
                acc[u] = __builtin_amdgcn_mfma_f32_16x16x32_bf16(ahi, bl, acc[u], 0, 0, 0);
            }
        }

        int nb = m0 + q * 4;
        float dv[4];
        #pragma unroll
        for (int r = 0; r < 4; ++r)
            dv[r] = (nb + r < n) ? rsqrtf((float)(deg[nb + r] + 1)) : 0.f;
        #pragma unroll
        for (int u = 0; u < 4; ++u) {
            #pragma unroll
            for (int r = 0; r < 4; ++r) {
                int node = nb + r;
                if (node < n)
                    yb[(size_t)node * D_OUT + u * 16 + cl] = (__bf16)(dv[r] * acc[u][r]);
            }
        }
        return;
    }

    // ---------------- CSR-fill role ----------------
    int bin = b;

    // phase A: redundant per-block scan of bin counts
    int i0 = 2 * t, i1 = 2 * t + 1;
    int v0 = (i0 < nbins) ? bincur[i0] : 0;
    int v1 = (i1 < nbins) ? bincur[i1] : 0;
    int s = v0 + v1;
    sc[t] = s;
    hist[t] = 0;                      // init for phase B
    __syncthreads();
    for (int o = 1; o < 256; o <<= 1) {
        int v = (t >= o) ? sc[t - o] : 0;
        __syncthreads();
        sc[t] += v;
        __syncthreads();
    }
    int excl = sc[t] - s;
    if (t == (bin >> 1)) sbase = (bin & 1) ? (excl + v0) : excl;
    if (bin == 0 && t == 255) off[n] = sc[255];
    __syncthreads();
    int binoff_b = sbase;

    // phase B: single pass -> ranks in registers
    int cnt = bincur[bin]; if (cnt > BINCAP) cnt = BINCAP;   // never-hit safety
    const unsigned* bp = pairs + (size_t)bin * BINCAP;
    unsigned vals[BINCAP / 256];
    int rks[BINCAP / 256];
    #pragma unroll
    for (int i = 0; i < BINCAP / 256; ++i) {
        int p = t + i * 256;
        if (p < cnt) {
            unsigned v = bp[p];
            vals[i] = v;
            rks[i] = atomicAdd(&hist[v & 255u], 1);
        }
    }
    __syncthreads();
    int own = hist[t];
    sc[t] = own;
    __syncthreads();
    for (int o = 1; o < 256; o <<= 1) {
        int v = (t >= o) ? sc[t - o] : 0;
        __syncthreads();
        sc[t] += v;
        __syncthreads();
    }
    int base = binoff_b + sc[t] - own;
    nbase[t] = base;
    int node = (bin << BINSHIFT) + t;
    if (node < n) off[node] = base;
    __syncthreads();
    #pragma unroll
    for (int i = 0; i < BINCAP / 256; ++i) {
        int p = t + i * 256;
        if (p < cnt) {
            unsigned v = vals[i];
            srcs[nbase[v & 255u] + rks[i]] = (int)(v >> 8);
        }
    }
}

// ---- CSR gather-aggregate: eighth-wave per edge, b128 loads ----------------
__device__ __forceinline__ void acc_row4(uintx4 v, float (&a)[8]) {
    #pragma unroll
    for (int k = 0; k < 4; ++k) {
        a[2 * k]     += __uint_as_float(v[k] << 16);
        a[2 * k + 1] += __uint_as_float(v[k] & 0xffff0000u);
    }
}

__global__ __launch_bounds__(256) void k_aggregate(
        const int* __restrict__ off, const int* __restrict__ srcs,
        const unsigned* __restrict__ ybf, const int* __restrict__ deg,
        const float* __restrict__ bnsc, const float* __restrict__ bnsh,
        float* __restrict__ out, int n) {
    int node = blockIdx.x * 4 + (threadIdx.x >> 6);
    if (node >= n) return;
    int lane = threadIdx.x & 63;
    int g = lane >> 3, sl = lane & 7;        // edge-group, sub-lane (8 channels)
    int s = off[node], e2 = off[node + 1];

    float a[8] = {0.f, 0.f, 0.f, 0.f, 0.f, 0.f, 0.f, 0.f};
    float dv = 0.f;
    floatx4 bs0, bs1, bh0, bh1;
    if (g == 0) {                            // self-loop + epilogue params
        dv = rsqrtf((float)(deg[node] + 1));
        bs0 = *(const floatx4*)(bnsc + sl * 8);
        bs1 = *(const floatx4*)(bnsc + sl * 8 + 4);
        bh0 = *(const floatx4*)(bnsh + sl * 8);
        bh1 = *(const floatx4*)(bnsh + sl * 8 + 4);
        uintx4 v = *(const uintx4*)(ybf + (size_t)node * 32 + sl * 4);
        acc_row4(v, a);
    }

    int e = s + g;
    for (; e + 24 < e2; e += 32) {           // 4 rows in flight per group
        int r0 = srcs[e], r1 = srcs[e + 8], r2 = srcs[e + 16], r3 = srcs[e + 24];
        uintx4 v0 = *(const uintx4*)(ybf + (size_t)r0 * 32 + sl * 4);
        uintx4 v1 = *(const uintx4*)(ybf + (size_t)r1 * 32 + sl * 4);
        uintx4 v2 = *(const uintx4*)(ybf + (size_t)r2 * 32 + sl * 4);
        uintx4 v3 = *(const uintx4*)(ybf + (size_t)r3 * 32 + sl * 4);
        acc_row4(v0, a);
        acc_row4(v1, a);
        acc_row4(v2, a);
        acc_row4(v3, a);
    }
    for (; e + 8 < e2; e += 16) {            // 2 rows in flight
        int r0 = srcs[e], r1 = srcs[e + 8];
        uintx4 v0 = *(const uintx4*)(ybf + (size_t)r0 * 32 + sl * 4);
        uintx4 v1 = *(const uintx4*)(ybf + (size_t)r1 * 32 + sl * 4);
        acc_row4(v0, a);
        acc_row4(v1, a);
    }
    for (; e < e2; e += 8) {
        uintx4 v = *(const uintx4*)(ybf + (size_t)srcs[e] * 32 + sl * 4);
        acc_row4(v, a);
    }

    #pragma unroll
    for (int k = 0; k < 8; ++k) {
        a[k] += __shfl_xor(a[k], 8);
        a[k] += __shfl_xor(a[k], 16);
        a[k] += __shfl_xor(a[k], 32);
    }

    if (g == 0) {
        float o[8];
        #pragma unroll
        for (int k = 0; k < 4; ++k) {
            o[k]     = fmaf(dv * a[k],     bs0[k], bh0[k]);
            o[4 + k] = fmaf(dv * a[4 + k], bs1[k], bh1[k]);
        }
        floatx4 w0 = { fmaxf(o[0], 0.f), fmaxf(o[1], 0.f),
                       fmaxf(o[2], 0.f), fmaxf(o[3], 0.f) };
        floatx4 w1 = { fmaxf(o[4], 0.f), fmaxf(o[5], 0.f),
                       fmaxf(o[6], 0.f), fmaxf(o[7], 0.f) };
        *(floatx4*)(out + (size_t)node * D_OUT + sl * 8) = w0;
        *(floatx4*)(out + (size_t)node * D_OUT + sl * 8 + 4) = w1;
    }
}

static inline char* align_up(char* p, size_t a) {
    return (char*)(((uintptr_t)p + a - 1) & ~(uintptr_t)(a - 1));
}

extern "C" void kernel_launch(void* const* d_in, const int* in_sizes, int n_in,
                              void* d_out, int out_size, void* d_ws, size_t ws_size,
                              hipStream_t stream) {
    const float* x     = (const float*)d_in[0];
    const int*   ei    = (const int*)d_in[1];
    const float* W     = (const float*)d_in[2];
    const float* bias  = (const float*)d_in[3];
    const float* gamma = (const float*)d_in[4];
    const float* beta  = (const float*)d_in[5];
    const float* rmean = (const float*)d_in[6];
    const float* rvar  = (const float*)d_in[7];
    float* out = (float*)d_out;

    int N = in_sizes[0] / D_IN;
    int E = in_sizes[1] / 2;
    int nbins = (N + (1 << BINSHIFT) - 1) >> BINSHIFT;   // 391 for N=100000
    int nchunks = (E + PCHUNK - 1) / PCHUNK;             // 196 for E=1.6M

    char* p = (char*)d_ws;
    int*      bincur = (int*)p;         p += 512 * 4;
    int*      deg    = (int*)p;         p += (size_t)N * 4;       p = align_up(p, 256);
    int*      off    = (int*)p;         p += (size_t)(N + 1) * 4; p = align_up(p, 256);
    float*    bnsc   = (float*)p;       p += D_OUT * 4;
    float*    bnsh   = (float*)p;       p += D_OUT * 4;           p = align_up(p, 256);
    __bf16*   whi    = (__bf16*)p;      p += (size_t)D_OUT * D_IN * 2; p = align_up(p, 256);
    __bf16*   wlo    = (__bf16*)p;      p += (size_t)D_OUT * D_IN * 2; p = align_up(p, 256);
    __bf16*   yb     = (__bf16*)p;      p += (size_t)N * D_OUT * 2;    p = align_up(p, 256);
    int*      srcs   = (int*)p;         p += (size_t)E * 4;       p = align_up(p, 256);
    unsigned* pairs  = (unsigned*)p;    // nbins * BINCAP * 4 bytes (~7.2 MB)

    // one memset covers bincur (2KB) + deg (N*4, contiguous)
    hipMemsetAsync(bincur, 0, 512 * 4 + (size_t)N * 4, stream);
    k_prepart<<<9 + nchunks, 256, 0, stream>>>(W, whi, wlo, bias, gamma, beta,
                                               rmean, rvar, bnsc, bnsh,
                                               ei, bincur, deg, pairs, E, nbins);
    k_fillgemm<<<nbins + (N + 63) / 64, 256, 0, stream>>>(
        pairs, bincur, off, srcs, x, whi, wlo, deg, yb, N, nbins);
    k_aggregate<<<(N + 3) / 4, 256, 0, stream>>>(off, srcs, (const unsigned*)yb,
                                                 deg, bnsc, bnsh, out, N);
}

// Round 14
// 276.379 us; speedup vs baseline: 1.1689x; 1.1689x over previous
//
#include <hip/hip_runtime.h>
#include <hip/hip_bf16.h>

#define D_IN 256
#define D_OUT 64
#define BN_EPS 1e-5f

#define BINSHIFT 8                 // 256 nodes per bin
#define BINCAP 4608                // >= max edges per bin (mean 4092, +8 sigma)
#define PCHUNK 8192                // edges per k_part block

typedef __attribute__((ext_vector_type(4))) float floatx4;
typedef __attribute__((ext_vector_type(8))) __bf16 bf16x8;
typedef __attribute__((ext_vector_type(4))) unsigned uintx4;

// ---- fused prep + binned partition ----------------------------------------
// blocks 0..7 : W split into whi/wlo (MFMA B-fragment order)
// block  8    : BN scale/shift precompute
// blocks 9+   : edge partition chunks (bincur pre-zeroed by hipMemsetAsync)
__global__ __launch_bounds__(256) void k_prepart(
        const float* __restrict__ W, __bf16* __restrict__ whi, __bf16* __restrict__ wlo,
        const float* __restrict__ bias, const float* __restrict__ gamma,
        const float* __restrict__ beta, const float* __restrict__ rmean,
        const float* __restrict__ rvar,
        float* __restrict__ bnsc, float* __restrict__ bnsh,
        const int* __restrict__ ei, int* __restrict__ bincur,
        unsigned* __restrict__ pairs, int E, int nbins) {
    int b = blockIdx.x, t = threadIdx.x;
    if (b < 8) {                       // W split: tid 0..2047
        int tid = b * 256 + t;
        int lane = tid & 63, c = (tid >> 6) & 7, tt = tid >> 9;
        int row = tt * 16 + (lane & 15);
        int k0 = c * 32 + (lane >> 4) * 8;
        size_t dst = (size_t)tid * 8;
        #pragma unroll
        for (int j = 0; j < 8; ++j) {
            float w = W[(size_t)row * D_IN + k0 + j];
            __bf16 h = (__bf16)w;
            whi[dst + j] = h;
            wlo[dst + j] = (__bf16)(w - (float)h);
        }
        return;
    }
    if (b == 8) {                      // BN params
        if (t < D_OUT) {
            float sc = rsqrtf(rvar[t] + BN_EPS) * gamma[t];
            bnsc[t] = sc;
            bnsh[t] = (bias[t] - rmean[t]) * sc + beta[t];
        }
        return;
    }

    // ---- partition role ----
    __shared__ int hist[512];
    __shared__ int base[512];
    int e0 = (b - 9) * PCHUNK;

    for (int j = t; j < nbins; j += 256) hist[j] = 0;
    __syncthreads();

    int cols[PCHUNK / 256];
    int rows[PCHUNK / 256];
    int ranks[PCHUNK / 256];
    #pragma unroll
    for (int i = 0; i < PCHUNK / 256; ++i) {
        int e = e0 + i * 256 + t;
        if (e < E) {
            int c = ei[E + e];
            cols[i] = c;
            rows[i] = ei[e];
            ranks[i] = atomicAdd(&hist[c >> BINSHIFT], 1);
        }
    }
    __syncthreads();
    for (int j = t; j < nbins; j += 256)
        base[j] = atomicAdd(&bincur[j], hist[j]);
    __syncthreads();
    #pragma unroll
    for (int i = 0; i < PCHUNK / 256; ++i) {
        int e = e0 + i * 256 + t;
        if (e < E) {
            int c = cols[i];
            int bin = c >> BINSHIFT;
            int pos = base[bin] + ranks[i];
            if (pos >= BINCAP) pos = BINCAP - 1;     // never-hit safety
            pairs[(size_t)bin * BINCAP + pos] =
                ((unsigned)rows[i] << 8) | (unsigned)(c & 255);
        }
    }
}

// ---- per-bin CSR fill: fused bin-offset scan + SINGLE pass over pairs ------
__global__ __launch_bounds__(256) void k_fill3(
        const unsigned* __restrict__ pairs, const int* __restrict__ bincur,
        int* __restrict__ off, float* __restrict__ dinv,
        int* __restrict__ srcs, int n, int nbins) {
    __shared__ int hist[256];
    __shared__ int sc[256];
    __shared__ int nbase[256];
    __shared__ int sbase;
    int bin = blockIdx.x, t = threadIdx.x;

    // ---- phase A: redundant per-block scan of bin counts ----
    int i0 = 2 * t, i1 = 2 * t + 1;
    int v0 = (i0 < nbins) ? bincur[i0] : 0;
    int v1 = (i1 < nbins) ? bincur[i1] : 0;
    int s = v0 + v1;
    sc[t] = s;
    hist[t] = 0;                      // init for phase B
    __syncthreads();
    for (int o = 1; o < 256; o <<= 1) {
        int v = (t >= o) ? sc[t - o] : 0;
        __syncthreads();
        sc[t] += v;
        __syncthreads();
    }
    int excl = sc[t] - s;
    if (t == (bin >> 1)) sbase = (bin & 1) ? (excl + v0) : excl;
    if (bin == 0 && t == 255) off[n] = sc[255];
    __syncthreads();
    int binoff_b = sbase;

    // ---- phase B: single pass -> ranks in registers ----
    int cnt = bincur[bin]; if (cnt > BINCAP) cnt = BINCAP;   // never-hit safety
    const unsigned* bp = pairs + (size_t)bin * BINCAP;
    unsigned vals[BINCAP / 256];
    int rks[BINCAP / 256];
    #pragma unroll
    for (int i = 0; i < BINCAP / 256; ++i) {
        int p = t + i * 256;
        if (p < cnt) {
            unsigned v = bp[p];
            vals[i] = v;
            rks[i] = atomicAdd(&hist[v & 255u], 1);
        }
    }
    __syncthreads();
    int own = hist[t];
    sc[t] = own;
    __syncthreads();
    for (int o = 1; o < 256; o <<= 1) {
        int v = (t >= o) ? sc[t - o] : 0;
        __syncthreads();
        sc[t] += v;
        __syncthreads();
    }
    int base = binoff_b + sc[t] - own;
    nbase[t] = base;
    int node = (bin << BINSHIFT) + t;
    if (node < n) {
        off[node] = base;
        dinv[node] = rsqrtf((float)(own + 1));   // +1 self-loop
    }
    __syncthreads();
    #pragma unroll
    for (int i = 0; i < BINCAP / 256; ++i) {
        int p = t + i * 256;
        if (p < cnt) {
            unsigned v = vals[i];
            srcs[nbase[v & 255u] + rks[i]] = (int)(v >> 8);
        }
    }
}

// ---- y(bf16) = dinv * (x @ W^T) via split-bf16 MFMA; no LDS ----------------
__global__ __launch_bounds__(256) void k_gemm(
        const float* __restrict__ x, const __bf16* __restrict__ whi,
        const __bf16* __restrict__ wlo, const float* __restrict__ dinv,
        __bf16* __restrict__ yb, int n) {
    int wave = threadIdx.x >> 6;
    int lane = threadIdx.x & 63;
    int m0 = blockIdx.x * 64 + wave * 16;
    if (m0 >= n) return;
    int q = lane >> 4, cl = lane & 15;
    int arow = m0 + cl; if (arow >= n) arow = n - 1;   // clamp (tail rows unused)
    const float* ap = x + (size_t)arow * D_IN + q * 8;

    floatx4 acc[4] = {{0.f,0.f,0.f,0.f},{0.f,0.f,0.f,0.f},
                      {0.f,0.f,0.f,0.f},{0.f,0.f,0.f,0.f}};

    #pragma unroll
    for (int c = 0; c < 8; ++c) {
        floatx4 a0 = *(const floatx4*)(ap + c * 32);
        floatx4 a1 = *(const floatx4*)(ap + c * 32 + 4);
        bf16x8 ahi, alo;
        #pragma unroll
        for (int j = 0; j < 4; ++j) {
            __bf16 h0 = (__bf16)a0[j];
            __bf16 h1 = (__bf16)a1[j];
            ahi[j] = h0;     alo[j] = (__bf16)(a0[j] - (float)h0);
            ahi[4 + j] = h1; alo[4 + j] = (__bf16)(a1[j] - (float)h1);
        }
        #pragma unroll
        for (int t = 0; t < 4; ++t) {
            size_t fo = ((size_t)(t * 8 + c) * 64 + lane) * 8;
            bf16x8 bh = *(const bf16x8*)(whi + fo);
            bf16x8 bl = *(const bf16x8*)(wlo + fo);
            acc[t] = __builtin_amdgcn_mfma_f32_16x16x32_bf16(ahi, bh, acc[t], 0, 0, 0);
            acc[t] = __builtin_amdgcn_mfma_f32_16x16x32_bf16(alo, bh, acc[t], 0, 0, 0);
            acc[t] = __builtin_amdgcn_mfma_f32_16x16x32_bf16(ahi, bl, acc[t], 0, 0, 0);
        }
    }

    int nb = m0 + q * 4;
    float dv[4];
    #pragma unroll
    for (int r = 0; r < 4; ++r) dv[r] = (nb + r < n) ? dinv[nb + r] : 0.f;
    #pragma unroll
    for (int t = 0; t < 4; ++t) {
        #pragma unroll
        for (int r = 0; r < 4; ++r) {
            int node = nb + r;
            if (node < n)
                yb[(size_t)node * D_OUT + t * 16 + cl] = (__bf16)(dv[r] * acc[t][r]);
        }
    }
}

// ---- CSR gather-aggregate: eighth-wave per edge, b128 loads ----------------
__device__ __forceinline__ void acc_row4(uintx4 v, float (&a)[8]) {
    #pragma unroll
    for (int k = 0; k < 4; ++k) {
        a[2 * k]     += __uint_as_float(v[k] << 16);
        a[2 * k + 1] += __uint_as_float(v[k] & 0xffff0000u);
    }
}

__global__ __launch_bounds__(256) void k_aggregate(
        const int* __restrict__ off, const int* __restrict__ srcs,
        const unsigned* __restrict__ ybf, const float* __restrict__ dinv,
        const float* __restrict__ bnsc, const float* __restrict__ bnsh,
        float* __restrict__ out, int n) {
    int node = blockIdx.x * 4 + (threadIdx.x >> 6);
    if (node >= n) return;
    int lane = threadIdx.x & 63;
    int g = lane >> 3, sl = lane & 7;        // edge-group, sub-lane (8 channels)
    int s = off[node], e2 = off[node + 1];

    float a[8] = {0.f, 0.f, 0.f, 0.f, 0.f, 0.f, 0.f, 0.f};
    float dv = 0.f;
    floatx4 bs0, bs1, bh0, bh1;
    if (g == 0) {                            // self-loop + epilogue params
        dv = dinv[node];
        bs0 = *(const floatx4*)(bnsc + sl * 8);
        bs1 = *(const floatx4*)(bnsc + sl * 8 + 4);
        bh0 = *(const floatx4*)(bnsh + sl * 8);
        bh1 = *(const floatx4*)(bnsh + sl * 8 + 4);
        uintx4 v = *(const uintx4*)(ybf + (size_t)node * 32 + sl * 4);
        acc_row4(v, a);
    }

    int e = s + g;
    for (; e + 24 < e2; e += 32) {           // 4 rows in flight per group
        int r0 = srcs[e], r1 = srcs[e + 8], r2 = srcs[e + 16], r3 = srcs[e + 24];
        uintx4 v0 = *(const uintx4*)(ybf + (size_t)r0 * 32 + sl * 4);
        uintx4 v1 = *(const uintx4*)(ybf + (size_t)r1 * 32 + sl * 4);
        uintx4 v2 = *(const uintx4*)(ybf + (size_t)r2 * 32 + sl * 4);
        uintx4 v3 = *(const uintx4*)(ybf + (size_t)r3 * 32 + sl * 4);
        acc_row4(v0, a);
        acc_row4(v1, a);
        acc_row4(v2, a);
        acc_row4(v3, a);
    }
    for (; e + 8 < e2; e += 16) {            // 2 rows in flight
        int r0 = srcs[e], r1 = srcs[e + 8];
        uintx4 v0 = *(const uintx4*)(ybf + (size_t)r0 * 32 + sl * 4);
        uintx4 v1 = *(const uintx4*)(ybf + (size_t)r1 * 32 + sl * 4);
        acc_row4(v0, a);
        acc_row4(v1, a);
    }
    for (; e < e2; e += 8) {
        uintx4 v = *(const uintx4*)(ybf + (size_t)srcs[e] * 32 + sl * 4);
        acc_row4(v, a);
    }

    #pragma unroll
    for (int k = 0; k < 8; ++k) {
        a[k] += __shfl_xor(a[k], 8);
        a[k] += __shfl_xor(a[k], 16);
        a[k] += __shfl_xor(a[k], 32);
    }

    if (g == 0) {
        float o[8];
        #pragma unroll
        for (int k = 0; k < 4; ++k) {
            o[k]     = fmaf(dv * a[k],     bs0[k], bh0[k]);
            o[4 + k] = fmaf(dv * a[4 + k], bs1[k], bh1[k]);
        }
        floatx4 w0 = { fmaxf(o[0], 0.f), fmaxf(o[1], 0.f),
                       fmaxf(o[2], 0.f), fmaxf(o[3], 0.f) };
        floatx4 w1 = { fmaxf(o[4], 0.f), fmaxf(o[5], 0.f),
                       fmaxf(o[6], 0.f), fmaxf(o[7], 0.f) };
        *(floatx4*)(out + (size_t)node * D_OUT + sl * 8) = w0;
        *(floatx4*)(out + (size_t)node * D_OUT + sl * 8 + 4) = w1;
    }
}

static inline char* align_up(char* p, size_t a) {
    return (char*)(((uintptr_t)p + a - 1) & ~(uintptr_t)(a - 1));
}

extern "C" void kernel_launch(void* const* d_in, const int* in_sizes, int n_in,
                              void* d_out, int out_size, void* d_ws, size_t ws_size,
                              hipStream_t stream) {
    const float* x     = (const float*)d_in[0];
    const int*   ei    = (const int*)d_in[1];
    const float* W     = (const float*)d_in[2];
    const float* bias  = (const float*)d_in[3];
    const float* gamma = (const float*)d_in[4];
    const float* beta  = (const float*)d_in[5];
    const float* rmean = (const float*)d_in[6];
    const float* rvar  = (const float*)d_in[7];
    float* out = (float*)d_out;

    int N = in_sizes[0] / D_IN;
    int E = in_sizes[1] / 2;
    int nbins = (N + (1 << BINSHIFT) - 1) >> BINSHIFT;   // 391 for N=100000
    int nchunks = (E + PCHUNK - 1) / PCHUNK;             // 196 for E=1.6M

    char* p = (char*)d_ws;
    int*      bincur = (int*)p;         p += 512 * 4;
    int*      off    = (int*)p;         p += (size_t)(N + 1) * 4; p = align_up(p, 256);
    float*    dinv   = (float*)p;       p += (size_t)N * 4;       p = align_up(p, 256);
    float*    bnsc   = (float*)p;       p += D_OUT * 4;
    float*    bnsh   = (float*)p;       p += D_OUT * 4;           p = align_up(p, 256);
    __bf16*   whi    = (__bf16*)p;      p += (size_t)D_OUT * D_IN * 2; p = align_up(p, 256);
    __bf16*   wlo    = (__bf16*)p;      p += (size_t)D_OUT * D_IN * 2; p = align_up(p, 256);
    __bf16*   yb     = (__bf16*)p;      p += (size_t)N * D_OUT * 2;    p = align_up(p, 256);
    int*      srcs   = (int*)p;         p += (size_t)E * 4;       p = align_up(p, 256);
    unsigned* pairs  = (unsigned*)p;    // nbins * BINCAP * 4 bytes (~7.2 MB)

    hipMemsetAsync(bincur, 0, 512 * 4, stream);
    k_prepart<<<9 + nchunks, 256, 0, stream>>>(W, whi, wlo, bias, gamma, beta,
                                               rmean, rvar, bnsc, bnsh,
                                               ei, bincur, pairs, E, nbins);
    k_fill3<<<nbins, 256, 0, stream>>>(pairs, bincur, off, dinv, srcs, N, nbins);
    k_gemm<<<(N + 63) / 64, 256, 0, stream>>>(x, whi, wlo, dinv, yb, N);
    k_aggregate<<<(N + 3) / 4, 256, 0, stream>>>(off, srcs, (const unsigned*)yb,
                                                 dinv, bnsc, bnsh, out, N);
}